// Round 1
// baseline (556.767 us; speedup 1.0000x reference)
//
#include <hip/hip_runtime.h>
#include <math.h>

#define Dd 32
#define Hh 256

// One block per sample. 256 threads.
// Fused: score-net fwd, Jacobian trace (fwd-mode, 32 tangent dirs),
//        cov-net fwd, cov divergence.
__global__ __launch_bounds__(256) void sbd_fused(
    const float* __restrict__ x,
    const float* __restrict__ sW1, const float* __restrict__ sb1,
    const float* __restrict__ sW2, const float* __restrict__ sb2,
    const float* __restrict__ sW3, const float* __restrict__ sb3,
    const float* __restrict__ cW1, const float* __restrict__ cb1,
    const float* __restrict__ cW2, const float* __restrict__ cb2,
    const float* __restrict__ cW3, const float* __restrict__ cb3,
    float* __restrict__ out, int B)
{
    __shared__ float xs[Dd];
    __shared__ float h1[Hh], t1[Hh], h2[Hh], t2[Hh];
    __shared__ float S1[Dd * Hh];   // A1 (tangent layer-1, scaled) then Mt (cov tangent layer-2)
    __shared__ float red[1024];     // reductions / divergence partials

    const int t = threadIdx.x;
    const int b = blockIdx.x;

    float* out_score = out;                       // [B, 32]
    float* out_trace = out + (size_t)B * Dd;      // [B]
    float* out_cov   = out_trace + B;             // [B, 32, 32]
    float* out_cdiv  = out_cov + (size_t)B * Dd * Dd; // [B, 32]

    if (t < Dd) xs[t] = x[b * Dd + t];
    __syncthreads();

    // ===================== score net =====================
    {
        float z = sb1[t];
        #pragma unroll
        for (int i = 0; i < Dd; ++i) z += xs[i] * sW1[i * Hh + t];
        float h = tanhf(z);
        h1[t] = h; t1[t] = 1.0f - h * h;
    }
    __syncthreads();
    {
        float z = sb2[t];
        for (int k = 0; k < Hh; k += 4) {
            float4 hk = *(const float4*)&h1[k];
            z += hk.x * sW2[(k + 0) * Hh + t];
            z += hk.y * sW2[(k + 1) * Hh + t];
            z += hk.z * sW2[(k + 2) * Hh + t];
            z += hk.w * sW2[(k + 3) * Hh + t];
        }
        float h = tanhf(z);
        h2[t] = h; t2[t] = 1.0f - h * h;
        // A1[i][k] = sW1[i,k] * t1[k]  (this thread fills column k = t)
        float tt = t1[t];
        #pragma unroll
        for (int i = 0; i < Dd; ++i) S1[i * Hh + t] = sW1[i * Hh + t] * tt;
    }
    __syncthreads();

    // score head (threads 0..31)
    if (t < Dd) {
        float z = sb3[t];
        for (int k = 0; k < Hh; ++k) z += h2[k] * sW3[k * Dd + t];
        out_score[b * Dd + t] = z;
    }

    // tangent GEMM: acc[i] = sum_k A1[i][k] * sW2[k, t]
    float acc[Dd];
    #pragma unroll
    for (int i = 0; i < Dd; ++i) acc[i] = 0.f;
    for (int k = 0; k < Hh; k += 4) {
        float w0 = sW2[(k + 0) * Hh + t];
        float w1 = sW2[(k + 1) * Hh + t];
        float w2 = sW2[(k + 2) * Hh + t];
        float w3 = sW2[(k + 3) * Hh + t];
        #pragma unroll
        for (int i = 0; i < Dd; ++i) {
            float4 a = *(const float4*)&S1[i * Hh + k];  // wave-uniform broadcast
            acc[i] += a.x * w0 + a.y * w1 + a.z * w2 + a.w * w3;
        }
    }
    // trace partial: p_t = t2[t] * sum_i acc[i] * sW3[t, i]
    {
        float p = 0.f;
        #pragma unroll
        for (int i = 0; i < Dd; ++i) p += acc[i] * sW3[t * Dd + i];
        p *= t2[t];
        #pragma unroll
        for (int off = 32; off > 0; off >>= 1) p += __shfl_down(p, off, 64);
        if ((t & 63) == 0) red[t >> 6] = p;
    }
    __syncthreads();
    if (t == 0) out_trace[b] = red[0] + red[1] + red[2] + red[3];
    __syncthreads();

    // ===================== cov net =====================
    {
        float z = cb1[t];
        #pragma unroll
        for (int i = 0; i < Dd; ++i) z += xs[i] * cW1[i * Hh + t];
        float h = tanhf(z);
        h1[t] = h; t1[t] = 1.0f - h * h;
    }
    __syncthreads();
    {
        float z = cb2[t];
        for (int k = 0; k < Hh; k += 4) {
            float4 hk = *(const float4*)&h1[k];
            z += hk.x * cW2[(k + 0) * Hh + t];
            z += hk.y * cW2[(k + 1) * Hh + t];
            z += hk.z * cW2[(k + 2) * Hh + t];
            z += hk.w * cW2[(k + 3) * Hh + t];
        }
        float h = tanhf(z);
        h2[t] = h; t2[t] = 1.0f - h * h;
        float tt = t1[t];
        #pragma unroll
        for (int i = 0; i < Dd; ++i) S1[i * Hh + t] = cW1[i * Hh + t] * tt;
    }
    __syncthreads();

    // cov tangent GEMM: acc[j] = sum_k A1c[j][k] * cW2[k, t]
    #pragma unroll
    for (int i = 0; i < Dd; ++i) acc[i] = 0.f;
    for (int k = 0; k < Hh; k += 4) {
        float w0 = cW2[(k + 0) * Hh + t];
        float w1 = cW2[(k + 1) * Hh + t];
        float w2 = cW2[(k + 2) * Hh + t];
        float w3 = cW2[(k + 3) * Hh + t];
        #pragma unroll
        for (int i = 0; i < Dd; ++i) {
            float4 a = *(const float4*)&S1[i * Hh + k];
            acc[i] += a.x * w0 + a.y * w1 + a.z * w2 + a.w * w3;
        }
    }
    __syncthreads();   // all reads of S1 (A1c) finished before reuse as Mt
    {
        // Mt[t][j] = t2c[t] * acc[j]; staggered j order -> conflict-free writes
        float tt = t2[t];
        #pragma unroll
        for (int jj = 0; jj < Dd; ++jj) {
            int j = (jj + t) & (Dd - 1);
            S1[t * Dd + j] = tt * acc[j];
        }
    }
    __syncthreads();

    // fused pass over cW3: cov output + divergence partials
    {
        int j = t & 31;  // col & 31 is identical for all 4 q since 256 % 32 == 0
        float cv0 = cb3[t], cv1 = cb3[t + 256], cv2 = cb3[t + 512], cv3 = cb3[t + 768];
        float dv0 = 0.f, dv1 = 0.f, dv2 = 0.f, dv3 = 0.f;
        for (int kk = 0; kk < Hh; ++kk) {
            float m = S1[kk * Dd + j];
            float h = h2[kk];
            const float* wrow = &cW3[kk * 1024 + t];
            float w0 = wrow[0], w1 = wrow[256], w2 = wrow[512], w3 = wrow[768];
            cv0 += h * w0;  dv0 += m * w0;
            cv1 += h * w1;  dv1 += m * w1;
            cv2 += h * w2;  dv2 += m * w2;
            cv3 += h * w3;  dv3 += m * w3;
        }
        float* co = &out_cov[(size_t)b * 1024];
        co[t] = cv0; co[t + 256] = cv1; co[t + 512] = cv2; co[t + 768] = cv3;
        red[t] = dv0; red[t + 256] = dv1; red[t + 512] = dv2; red[t + 768] = dv3;
    }
    __syncthreads();
    if (t < Dd) {
        float s = 0.f;
        #pragma unroll
        for (int jj = 0; jj < Dd; ++jj) {
            int j = (jj + t) & 31;      // staggered -> conflict-free reads
            s += red[t * Dd + j];
        }
        out_cdiv[b * Dd + t] = s;
    }
}

extern "C" void kernel_launch(void* const* d_in, const int* in_sizes, int n_in,
                              void* d_out, int out_size, void* d_ws, size_t ws_size,
                              hipStream_t stream) {
    const float* x   = (const float*)d_in[0];
    const float* sW1 = (const float*)d_in[1];
    const float* sb1 = (const float*)d_in[2];
    const float* sW2 = (const float*)d_in[3];
    const float* sb2 = (const float*)d_in[4];
    const float* sW3 = (const float*)d_in[5];
    const float* sb3 = (const float*)d_in[6];
    const float* cW1 = (const float*)d_in[7];
    const float* cb1 = (const float*)d_in[8];
    const float* cW2 = (const float*)d_in[9];
    const float* cb2 = (const float*)d_in[10];
    const float* cW3 = (const float*)d_in[11];
    const float* cb3 = (const float*)d_in[12];

    const int B = in_sizes[0] / Dd;

    sbd_fused<<<dim3(B), dim3(256), 0, stream>>>(
        x, sW1, sb1, sW2, sb2, sW3, sb3,
        cW1, cb1, cW2, cb2, cW3, cb3,
        (float*)d_out, B);
}

// Round 2
// 220.891 us; speedup vs baseline: 2.5206x; 2.5206x over previous
//
#include <hip/hip_runtime.h>
#include <math.h>

#define Dd 32
#define Hh 256

using short8  = __attribute__((ext_vector_type(8))) short;
using floatx4 = __attribute__((ext_vector_type(4))) float;

__device__ inline unsigned short f2bf(float f) {
    union { float f; unsigned u; } v; v.f = f;
    unsigned r = (v.u + 0x7FFFu + ((v.u >> 16) & 1u)) >> 16;
    return (unsigned short)r;
}
__device__ inline float bf2f(unsigned short h) {
    union { unsigned u; float f; } v; v.u = ((unsigned)h) << 16;
    return v.f;
}

// ============================================================================
// K0: precompute the 33 contraction matrices, bf16, B^T layout Mt[i][t][k]
//   i=0:  M[k,t] = sW2[k,t] * sum_m sW1[m,k]*sW3[t,m]           (trace)
//   i>=1: M[k,t] = cW2[k,t] * sum_j cW1[j,k]*cW3[t,(i-1)*32+j]  (divergence)
// grid (4 k-quarters, 33 i), 256 threads; thread = t-column.
// ============================================================================
__global__ __launch_bounds__(256) void k0_precompute(
    const float* __restrict__ sW1, const float* __restrict__ sW2, const float* __restrict__ sW3,
    const float* __restrict__ cW1, const float* __restrict__ cW2, const float* __restrict__ cW3,
    unsigned short* __restrict__ Mt)
{
    const int kq = blockIdx.x;      // k in [kq*64, kq*64+64)
    const int i  = blockIdx.y;      // 0..32
    const int tid = threadIdx.x;    // t column

    const float *W1, *W2, *C3;
    int cstride, coff;
    if (i == 0) { W1 = sW1; W2 = sW2; C3 = sW3; cstride = 32;   coff = 0; }
    else        { W1 = cW1; W2 = cW2; C3 = cW3; cstride = 1024; coff = (i - 1) * 32; }

    __shared__ float W1t[64][36];    // [k_local][j], padded
    __shared__ float Ct[256][33];    // [t][j], padded

    // stage Ct: thread t reads its 32 j-values (16B-aligned rows)
    {
        const float* src = C3 + (size_t)tid * cstride + coff;
        #pragma unroll
        for (int j4 = 0; j4 < 8; ++j4) {
            float4 v = *(const float4*)(src + j4 * 4);
            Ct[tid][j4 * 4 + 0] = v.x; Ct[tid][j4 * 4 + 1] = v.y;
            Ct[tid][j4 * 4 + 2] = v.z; Ct[tid][j4 * 4 + 3] = v.w;
        }
    }
    // stage W1t[k_local][j] = W1[j*256 + kq*64 + k_local]
    {
        int kl = tid & 63, jg = tid >> 6;
        #pragma unroll
        for (int jj = 0; jj < 8; ++jj) {
            int j = jg * 8 + jj;
            W1t[kl][j] = W1[j * 256 + kq * 64 + kl];
        }
    }
    __syncthreads();

    float ct[32];
    #pragma unroll
    for (int j = 0; j < 32; ++j) ct[j] = Ct[tid][j];

    for (int kg = 0; kg < 8; ++kg) {
        float acc[8];
        #pragma unroll
        for (int q = 0; q < 8; ++q) {
            float a = 0.f;
            #pragma unroll
            for (int j4 = 0; j4 < 8; ++j4) {
                float4 w = *(const float4*)&W1t[kg * 8 + q][j4 * 4];
                a += w.x * ct[j4 * 4 + 0] + w.y * ct[j4 * 4 + 1]
                   + w.z * ct[j4 * 4 + 2] + w.w * ct[j4 * 4 + 3];
            }
            acc[q] = a;
        }
        const int kbase = kq * 64 + kg * 8;
        short8 pk;
        #pragma unroll
        for (int q = 0; q < 8; ++q) {
            float m = acc[q] * W2[(size_t)(kbase + q) * 256 + tid];
            pk[q] = (short)f2bf(m);
        }
        // Mt layout: [i][t][k] bf16 (k contiguous) -> B^T rows for MFMA B-frags
        *(short8*)(Mt + (size_t)i * 65536 + (size_t)tid * 256 + kbase) = pk;
    }
}

// ============================================================================
// K1: fused forward for both nets, 8 samples/block, 512 threads.
// Outputs: score (fp32), cov (fp32), and t1/t2 per net as bf16 [B][256].
// ============================================================================
__global__ __launch_bounds__(512) void k1_forward(
    const float* __restrict__ x,
    const float* __restrict__ sW1, const float* __restrict__ sb1,
    const float* __restrict__ sW2, const float* __restrict__ sb2,
    const float* __restrict__ sW3, const float* __restrict__ sb3,
    const float* __restrict__ cW1, const float* __restrict__ cb1,
    const float* __restrict__ cW2, const float* __restrict__ cb2,
    const float* __restrict__ cW3, const float* __restrict__ cb3,
    float* __restrict__ out_score, float* __restrict__ out_cov,
    unsigned short* __restrict__ T1s, unsigned short* __restrict__ T2s,
    unsigned short* __restrict__ T1c, unsigned short* __restrict__ T2c)
{
    __shared__ float xT[32][8];          // [i][s]
    __shared__ float h1t[2][256][12];    // [net][k][s], padded to 12 for float4 align
    __shared__ float a2t[2][256][12];

    const int tid = threadIdx.x;
    const int sb = blockIdx.x * 8;

    if (tid < 256) {
        int s = tid >> 5, ii = tid & 31;
        xT[ii][s] = x[(sb + s) * Dd + ii];
    }
    __syncthreads();

    const int net = tid >> 8;       // 0 = score net, 1 = cov net
    const int col = tid & 255;
    const float* W1 = net ? cW1 : sW1;  const float* b1 = net ? cb1 : sb1;
    const float* W2 = net ? cW2 : sW2;  const float* b2 = net ? cb2 : sb2;
    unsigned short* T1 = net ? T1c : T1s;
    unsigned short* T2 = net ? T2c : T2s;

    float z[8];
    {
        float bb = b1[col];
        #pragma unroll
        for (int s = 0; s < 8; ++s) z[s] = bb;
    }
    #pragma unroll
    for (int ii = 0; ii < 32; ++ii) {
        float w = W1[ii * 256 + col];
        float4 xa = *(const float4*)&xT[ii][0];
        float4 xb = *(const float4*)&xT[ii][4];
        z[0] += w * xa.x; z[1] += w * xa.y; z[2] += w * xa.z; z[3] += w * xa.w;
        z[4] += w * xb.x; z[5] += w * xb.y; z[6] += w * xb.z; z[7] += w * xb.w;
    }
    #pragma unroll
    for (int s = 0; s < 8; ++s) {
        float h = tanhf(z[s]);
        h1t[net][col][s] = h;
        T1[(size_t)(sb + s) * 256 + col] = f2bf(1.0f - h * h);
    }
    __syncthreads();

    {
        float bb = b2[col];
        #pragma unroll
        for (int s = 0; s < 8; ++s) z[s] = bb;
    }
    #pragma unroll 4
    for (int k = 0; k < 256; ++k) {
        float w = W2[k * 256 + col];
        float4 ha = *(const float4*)&h1t[net][k][0];
        float4 hb = *(const float4*)&h1t[net][k][4];
        z[0] += w * ha.x; z[1] += w * ha.y; z[2] += w * ha.z; z[3] += w * ha.w;
        z[4] += w * hb.x; z[5] += w * hb.y; z[6] += w * hb.z; z[7] += w * hb.w;
    }
    #pragma unroll
    for (int s = 0; s < 8; ++s) {
        float h = tanhf(z[s]);
        a2t[net][col][s] = h;
        T2[(size_t)(sb + s) * 256 + col] = f2bf(1.0f - h * h);
    }
    __syncthreads();

    // score head: 32 m x 8 s on first 256 threads
    if (tid < 256) {
        int m = tid & 31, s = tid >> 5;
        float zz = sb3[m];
        #pragma unroll 4
        for (int k = 0; k < 256; ++k)
            zz += a2t[0][k][s] * sW3[k * 32 + m];
        out_score[(size_t)(sb + s) * 32 + m] = zz;
    }

    // cov head: 1024 cols x 8 s on all 512 threads (2 cols each)
    {
        const int c0 = tid, c1 = tid + 512;
        float cva[8], cvb[8];
        float ba = cb3[c0], bb2 = cb3[c1];
        #pragma unroll
        for (int s = 0; s < 8; ++s) { cva[s] = ba; cvb[s] = bb2; }
        #pragma unroll 4
        for (int k = 0; k < 256; ++k) {
            float w0 = cW3[(size_t)k * 1024 + c0];
            float w1 = cW3[(size_t)k * 1024 + c1];
            float4 aa = *(const float4*)&a2t[1][k][0];
            float4 ab = *(const float4*)&a2t[1][k][4];
            cva[0] += aa.x * w0; cva[1] += aa.y * w0; cva[2] += aa.z * w0; cva[3] += aa.w * w0;
            cva[4] += ab.x * w0; cva[5] += ab.y * w0; cva[6] += ab.z * w0; cva[7] += ab.w * w0;
            cvb[0] += aa.x * w1; cvb[1] += aa.y * w1; cvb[2] += aa.z * w1; cvb[3] += aa.w * w1;
            cvb[4] += ab.x * w1; cvb[5] += ab.y * w1; cvb[6] += ab.z * w1; cvb[7] += ab.w * w1;
        }
        #pragma unroll
        for (int s = 0; s < 8; ++s) {
            out_cov[(size_t)(sb + s) * 1024 + c0] = cva[s];
            out_cov[(size_t)(sb + s) * 1024 + c1] = cvb[s];
        }
    }
}

// ============================================================================
// K2: 33 GEMM-contractions via bf16 MFMA 16x16x32.
//   Z = T1_tile[64 x 256k] @ M_i  ; out[s] = sum_t T2[s,t] * Z[s,t]
// grid (32 s-tiles, 33 i), 256 threads (4 waves).
// Wave w: mh=w&1 (32-row half), nq=w>>1 (n-columns nq*64+{0,128}).
// A-frags preloaded in registers; B-frags streamed from global (L2-resident).
// ============================================================================
__global__ __launch_bounds__(256, 3) void k2_contract(
    const unsigned short* __restrict__ T1s, const unsigned short* __restrict__ T2s,
    const unsigned short* __restrict__ T1c, const unsigned short* __restrict__ T2c,
    const unsigned short* __restrict__ Mt,
    float* __restrict__ out_trace, float* __restrict__ out_cdiv)
{
    const int stile = blockIdx.x;
    const int i     = blockIdx.y;
    const int sbase = stile * 64;

    const unsigned short* A  = i ? T1c : T1s;
    const unsigned short* T2 = i ? T2c : T2s;
    const unsigned short* B  = Mt + (size_t)i * 65536;   // [t][k] bf16

    __shared__ unsigned short T2l[64 * 264];             // [s_local][t], padded
    __shared__ float red[2][64];

    const int tid  = threadIdx.x;
    const int w    = tid >> 6;
    const int lane = tid & 63;
    const int mh   = w & 1;
    const int nq   = w >> 1;
    const int g    = lane >> 4;
    const int r16  = lane & 15;

    // stage T2 tile into LDS (coalesced short8 reads)
    #pragma unroll
    for (int p = 0; p < 8; ++p) {
        int c = tid + p * 256;
        int row = c >> 5, cg = c & 31;
        short8 v = *(const short8*)(T2 + (size_t)(sbase + row) * 256 + cg * 8);
        *(short8*)&T2l[row * 264 + cg * 8] = v;
    }

    // preload all A-fragments for this wave's 32 rows (2 m-tiles x 8 k-steps)
    short8 af[2][8];
    #pragma unroll
    for (int mt = 0; mt < 2; ++mt)
        #pragma unroll
        for (int ks = 0; ks < 8; ++ks)
            af[mt][ks] = *(const short8*)(A + (size_t)(sbase + mh * 32 + mt * 16 + r16) * 256
                                            + ks * 32 + g * 8);
    __syncthreads();

    float pp[2][4];
    #pragma unroll
    for (int mt = 0; mt < 2; ++mt)
        #pragma unroll
        for (int reg = 0; reg < 4; ++reg) pp[mt][reg] = 0.f;

    #pragma unroll
    for (int sec = 0; sec < 2; ++sec) {
        const int nbase = nq * 64 + sec * 128;
        floatx4 acc[2][4];
        #pragma unroll
        for (int mt = 0; mt < 2; ++mt)
            #pragma unroll
            for (int nt = 0; nt < 4; ++nt)
                acc[mt][nt] = (floatx4){0.f, 0.f, 0.f, 0.f};

        #pragma unroll
        for (int ks = 0; ks < 8; ++ks) {
            short8 bfr[4];
            #pragma unroll
            for (int nt = 0; nt < 4; ++nt)
                bfr[nt] = *(const short8*)(B + (size_t)(nbase + nt * 16 + r16) * 256
                                             + ks * 32 + g * 8);
            #pragma unroll
            for (int nt = 0; nt < 4; ++nt) {
                acc[0][nt] = __builtin_amdgcn_mfma_f32_16x16x32_bf16(af[0][ks], bfr[nt], acc[0][nt], 0, 0, 0);
                acc[1][nt] = __builtin_amdgcn_mfma_f32_16x16x32_bf16(af[1][ks], bfr[nt], acc[1][nt], 0, 0, 0);
            }
        }

        // contract this sector's Z-tile with T2 weights
        #pragma unroll
        for (int mt = 0; mt < 2; ++mt)
            #pragma unroll
            for (int nt = 0; nt < 4; ++nt)
                #pragma unroll
                for (int reg = 0; reg < 4; ++reg) {
                    int r = mh * 32 + mt * 16 + g * 4 + reg;
                    int t = nbase + nt * 16 + r16;
                    float t2v = bf2f(T2l[r * 264 + t]);
                    pp[mt][reg] += acc[mt][nt][reg] * t2v;
                }
    }

    // reduce over the 16 lanes sharing (l>>4): xor over low-4 lane bits
    #pragma unroll
    for (int mt = 0; mt < 2; ++mt)
        #pragma unroll
        for (int reg = 0; reg < 4; ++reg) {
            float v = pp[mt][reg];
            v += __shfl_xor(v, 1, 64);
            v += __shfl_xor(v, 2, 64);
            v += __shfl_xor(v, 4, 64);
            v += __shfl_xor(v, 8, 64);
            pp[mt][reg] = v;
        }
    if (r16 == 0) {
        #pragma unroll
        for (int mt = 0; mt < 2; ++mt)
            #pragma unroll
            for (int reg = 0; reg < 4; ++reg) {
                int r = mh * 32 + mt * 16 + g * 4 + reg;
                red[nq][r] = pp[mt][reg];
            }
    }
    __syncthreads();
    if (tid < 64) {
        float v = red[0][tid] + red[1][tid];
        int sg = sbase + tid;
        if (i == 0) out_trace[sg] = v;
        else        out_cdiv[(size_t)sg * 32 + (i - 1)] = v;
    }
}

// ============================================================================
extern "C" void kernel_launch(void* const* d_in, const int* in_sizes, int n_in,
                              void* d_out, int out_size, void* d_ws, size_t ws_size,
                              hipStream_t stream) {
    const float* x   = (const float*)d_in[0];
    const float* sW1 = (const float*)d_in[1];
    const float* sb1 = (const float*)d_in[2];
    const float* sW2 = (const float*)d_in[3];
    const float* sb2 = (const float*)d_in[4];
    const float* sW3 = (const float*)d_in[5];
    const float* sb3 = (const float*)d_in[6];
    const float* cW1 = (const float*)d_in[7];
    const float* cb1 = (const float*)d_in[8];
    const float* cW2 = (const float*)d_in[9];
    const float* cb2 = (const float*)d_in[10];
    const float* cW3 = (const float*)d_in[11];
    const float* cb3 = (const float*)d_in[12];

    const int B = in_sizes[0] / Dd;   // 2048

    float* out       = (float*)d_out;
    float* out_score = out;                                  // [B,32]
    float* out_trace = out + (size_t)B * Dd;                 // [B]
    float* out_cov   = out_trace + B;                        // [B,32,32]
    float* out_cdiv  = out_cov + (size_t)B * Dd * Dd;        // [B,32]

    unsigned short* ws16 = (unsigned short*)d_ws;
    unsigned short* T1s = ws16;                              // [B][256] bf16
    unsigned short* T2s = ws16 + (size_t)B * 256;
    unsigned short* T1c = ws16 + (size_t)2 * B * 256;
    unsigned short* T2c = ws16 + (size_t)3 * B * 256;
    unsigned short* Mt  = ws16 + (size_t)4 * B * 256;        // [33][256][256] bf16

    k0_precompute<<<dim3(4, 33), dim3(256), 0, stream>>>(sW1, sW2, sW3, cW1, cW2, cW3, Mt);

    k1_forward<<<dim3(B / 8), dim3(512), 0, stream>>>(
        x, sW1, sb1, sW2, sb2, sW3, sb3,
        cW1, cb1, cW2, cb2, cW3, cb3,
        out_score, out_cov, T1s, T2s, T1c, T2c);

    k2_contract<<<dim3(B / 64, 33), dim3(256), 0, stream>>>(
        T1s, T2s, T1c, T2c, Mt, out_trace, out_cdiv);
}

// Round 3
// 194.288 us; speedup vs baseline: 2.8657x; 1.1369x over previous
//
#include <hip/hip_runtime.h>
#include <math.h>

#define Dd 32
#define Hh 256

using short8  = __attribute__((ext_vector_type(8))) short;
using floatx4 = __attribute__((ext_vector_type(4))) float;

__device__ inline unsigned short f2bf(float f) {
    union { float f; unsigned u; } v; v.f = f;
    unsigned r = (v.u + 0x7FFFu + ((v.u >> 16) & 1u)) >> 16;
    return (unsigned short)r;
}
__device__ inline float bf2f(unsigned short h) {
    union { unsigned u; float f; } v; v.u = ((unsigned)h) << 16;
    return v.f;
}

// ============================================================================
// KA: three partitions in one launch (grid.x = B/2 + 132 + 32):
//   [0, B/2):        forward layers 1-2 for one net x 4 samples (+ score head)
//   [B/2, B/2+132):  Mt precompute (kq 0..3, i 0..32)
//   [B/2+132, +32):  cW3 -> cW3t bf16 transpose-cast [1024][256]
// ============================================================================
__global__ __launch_bounds__(256) void ka_fused(
    const float* __restrict__ x,
    const float* __restrict__ sW1, const float* __restrict__ sb1,
    const float* __restrict__ sW2, const float* __restrict__ sb2,
    const float* __restrict__ sW3, const float* __restrict__ sb3,
    const float* __restrict__ cW1, const float* __restrict__ cb1,
    const float* __restrict__ cW2, const float* __restrict__ cb2,
    const float* __restrict__ cW3,
    float* __restrict__ out_score,
    unsigned short* __restrict__ T1s, unsigned short* __restrict__ T2s,
    unsigned short* __restrict__ T1c, unsigned short* __restrict__ T2c,
    unsigned short* __restrict__ H2c,
    unsigned short* __restrict__ Mt,  unsigned short* __restrict__ cW3t,
    int B)
{
    __shared__ char smem[33792];
    const int tid = threadIdx.x;
    const int bid = blockIdx.x;
    const int nfwd = B / 2;

    if (bid < nfwd) {
        // ---------------- forward: net = bid&1, samples sb..sb+3 ----------------
        const int net = bid & 1;
        const int sb  = (bid >> 1) * 4;
        float (*xT)[4]  = (float(*)[4])smem;            // [32][4]
        float (*h1t)[4] = (float(*)[4])(smem + 512);    // [256][4]
        float (*a2t)[4] = (float(*)[4])(smem + 4608);   // [256][4]

        if (tid < 128) {
            int s = tid >> 5, ii = tid & 31;
            xT[ii][s] = x[(sb + s) * Dd + ii];
        }
        __syncthreads();

        const float* W1 = net ? cW1 : sW1;  const float* b1 = net ? cb1 : sb1;
        const float* W2 = net ? cW2 : sW2;  const float* b2 = net ? cb2 : sb2;
        unsigned short* T1 = net ? T1c : T1s;
        unsigned short* T2 = net ? T2c : T2s;
        const int col = tid;

        float z[4];
        {
            float bb = b1[col];
            #pragma unroll
            for (int s = 0; s < 4; ++s) z[s] = bb;
        }
        #pragma unroll
        for (int ii = 0; ii < 32; ++ii) {
            float w = W1[ii * 256 + col];
            float4 xv = *(const float4*)xT[ii];
            z[0] += w * xv.x; z[1] += w * xv.y; z[2] += w * xv.z; z[3] += w * xv.w;
        }
        #pragma unroll
        for (int s = 0; s < 4; ++s) {
            float h = tanhf(z[s]);
            h1t[col][s] = h;
            T1[(size_t)(sb + s) * 256 + col] = f2bf(1.0f - h * h);
        }
        __syncthreads();

        {
            float bb = b2[col];
            #pragma unroll
            for (int s = 0; s < 4; ++s) z[s] = bb;
        }
        #pragma unroll 8
        for (int k = 0; k < 256; ++k) {
            float w = W2[k * 256 + col];
            float4 hv = *(const float4*)h1t[k];
            z[0] += w * hv.x; z[1] += w * hv.y; z[2] += w * hv.z; z[3] += w * hv.w;
        }
        #pragma unroll
        for (int s = 0; s < 4; ++s) {
            float h = tanhf(z[s]);
            T2[(size_t)(sb + s) * 256 + col] = f2bf(1.0f - h * h);
            if (net) H2c[(size_t)(sb + s) * 256 + col] = f2bf(h);
            else     a2t[col][s] = h;
        }
        __syncthreads();

        if (!net && tid < 128) {
            int m = tid & 31, s = tid >> 5;
            float zz = sb3[m];
            #pragma unroll 8
            for (int k = 0; k < 256; ++k)
                zz += a2t[k][s] * sW3[k * Dd + m];
            out_score[(size_t)(sb + s) * Dd + m] = zz;
        }
        return;
    }

    if (bid < nfwd + 132) {
        // ---------------- Mt precompute ----------------
        const int pb = bid - nfwd;
        const int kq = pb & 3;        // k quarter
        const int i  = pb >> 2;       // 0..32
        float (*W1t)[36] = (float(*)[36])smem;   // [64][36]

        const float *W1, *W2, *C3;
        int cstride, coff;
        if (i == 0) { W1 = sW1; W2 = sW2; C3 = sW3; cstride = 32;   coff = 0; }
        else        { W1 = cW1; W2 = cW2; C3 = cW3; cstride = 1024; coff = (i - 1) * 32; }

        {
            int kl = tid & 63, jg = tid >> 6;
            #pragma unroll
            for (int jj = 0; jj < 8; ++jj) {
                int j = jg * 8 + jj;
                W1t[kl][j] = W1[j * 256 + kq * 64 + kl];
            }
        }
        float ct[32];
        {
            const float* src = C3 + (size_t)tid * cstride + coff;
            #pragma unroll
            for (int j4 = 0; j4 < 8; ++j4) {
                float4 v = *(const float4*)(src + j4 * 4);
                ct[j4 * 4 + 0] = v.x; ct[j4 * 4 + 1] = v.y;
                ct[j4 * 4 + 2] = v.z; ct[j4 * 4 + 3] = v.w;
            }
        }
        __syncthreads();

        for (int kg = 0; kg < 8; ++kg) {
            const int kbase = kq * 64 + kg * 8;
            short8 pk;
            #pragma unroll
            for (int q = 0; q < 8; ++q) {
                float a = 0.f;
                #pragma unroll
                for (int j4 = 0; j4 < 8; ++j4) {
                    float4 w = *(const float4*)&W1t[kg * 8 + q][j4 * 4];
                    a += w.x * ct[j4 * 4 + 0] + w.y * ct[j4 * 4 + 1]
                       + w.z * ct[j4 * 4 + 2] + w.w * ct[j4 * 4 + 3];
                }
                float m = a * W2[(size_t)(kbase + q) * 256 + tid];
                pk[q] = (short)f2bf(m);
            }
            *(short8*)(Mt + (size_t)i * 65536 + (size_t)tid * 256 + kbase) = pk;
        }
        return;
    }

    // ---------------- cW3 transpose-cast: cW3t[n][k] = bf16(cW3[k][n]) ----------------
    {
        const int pb = bid - (nfwd + 132);
        const int n0 = pb * 32;
        float (*fl)[33] = (float(*)[33])smem;   // [256][33]

        #pragma unroll
        for (int p = 0; p < 32; ++p) {
            int kk = p * 8 + (tid >> 5);
            int nn = tid & 31;
            fl[kk][nn] = cW3[(size_t)kk * 1024 + n0 + nn];
        }
        __syncthreads();

        const int nn   = tid >> 3;
        const int kseg = (tid & 7) * 32;
        #pragma unroll
        for (int c = 0; c < 4; ++c) {
            short8 v;
            #pragma unroll
            for (int u = 0; u < 8; ++u)
                v[u] = (short)f2bf(fl[kseg + c * 8 + u][nn]);
            *(short8*)(cW3t + (size_t)(n0 + nn) * 256 + kseg + c * 8) = v;
        }
    }
}

// ============================================================================
// KB: 37 MFMA jobs x 32 s-tiles.
//   jobs 0..32 : Z = T1[64x256] @ Mt_i ; out = sum_t T2[s,t]*Z[s,t]  (trace/cdiv)
//   jobs 33..36: cov quarter: C = H2c[64x256] @ cW3t_slice^T + cb3   (fp32 out)
// 256 threads (4 waves). Wave w: mh=w&1 (32-row half), nq=w>>1.
// ============================================================================
__global__ __launch_bounds__(256, 4) void kb_mfma(
    const unsigned short* __restrict__ T1s, const unsigned short* __restrict__ T2s,
    const unsigned short* __restrict__ T1c, const unsigned short* __restrict__ T2c,
    const unsigned short* __restrict__ H2c,
    const unsigned short* __restrict__ Mt,  const unsigned short* __restrict__ cW3t,
    const float* __restrict__ cb3,
    float* __restrict__ out_trace, float* __restrict__ out_cdiv,
    float* __restrict__ out_cov)
{
    const int stile = blockIdx.x;
    const int job   = blockIdx.y;
    const int sbase = stile * 64;
    const bool contr = (job < 33);

    const unsigned short* A  = contr ? (job == 0 ? T1s : T1c) : H2c;
    const unsigned short* Bm = contr ? (Mt + (size_t)job * 65536)
                                     : (cW3t + (size_t)(job - 33) * 65536);
    const unsigned short* T2 = (job == 0) ? T2s : T2c;

    __shared__ unsigned short T2l[64 * 264];
    __shared__ float red[2][64];

    const int tid  = threadIdx.x;
    const int w    = tid >> 6;
    const int lane = tid & 63;
    const int mh   = w & 1;
    const int nq   = w >> 1;
    const int g    = lane >> 4;
    const int r16  = lane & 15;

    if (contr) {
        #pragma unroll
        for (int p = 0; p < 8; ++p) {
            int c = tid + p * 256;
            int row = c >> 5, cg = c & 31;
            *(short8*)&T2l[row * 264 + cg * 8] =
                *(const short8*)(T2 + (size_t)(sbase + row) * 256 + cg * 8);
        }
    }
    __syncthreads();

    float pp[2][4];
    #pragma unroll
    for (int mt = 0; mt < 2; ++mt)
        #pragma unroll
        for (int reg = 0; reg < 4; ++reg) pp[mt][reg] = 0.f;

    #pragma unroll
    for (int sec = 0; sec < 2; ++sec) {
        const int nbase = nq * 64 + sec * 128;
        floatx4 acc[2][4];
        #pragma unroll
        for (int mt = 0; mt < 2; ++mt)
            #pragma unroll
            for (int nt = 0; nt < 4; ++nt)
                acc[mt][nt] = (floatx4){0.f, 0.f, 0.f, 0.f};

        #pragma unroll
        for (int ks = 0; ks < 8; ++ks) {
            short8 af0 = *(const short8*)(A + (size_t)(sbase + mh * 32 + r16) * 256
                                            + ks * 32 + g * 8);
            short8 af1 = *(const short8*)(A + (size_t)(sbase + mh * 32 + 16 + r16) * 256
                                            + ks * 32 + g * 8);
            short8 bfr[4];
            #pragma unroll
            for (int nt = 0; nt < 4; ++nt)
                bfr[nt] = *(const short8*)(Bm + (size_t)(nbase + nt * 16 + r16) * 256
                                              + ks * 32 + g * 8);
            #pragma unroll
            for (int nt = 0; nt < 4; ++nt) {
                acc[0][nt] = __builtin_amdgcn_mfma_f32_16x16x32_bf16(af0, bfr[nt], acc[0][nt], 0, 0, 0);
                acc[1][nt] = __builtin_amdgcn_mfma_f32_16x16x32_bf16(af1, bfr[nt], acc[1][nt], 0, 0, 0);
            }
        }

        if (contr) {
            #pragma unroll
            for (int mt = 0; mt < 2; ++mt)
                #pragma unroll
                for (int nt = 0; nt < 4; ++nt)
                    #pragma unroll
                    for (int reg = 0; reg < 4; ++reg) {
                        int r = mh * 32 + mt * 16 + g * 4 + reg;
                        int t = nbase + nt * 16 + r16;
                        pp[mt][reg] += acc[mt][nt][reg] * bf2f(T2l[r * 264 + t]);
                    }
        } else {
            const int n0 = (job - 33) * 256;
            #pragma unroll
            for (int mt = 0; mt < 2; ++mt)
                #pragma unroll
                for (int nt = 0; nt < 4; ++nt) {
                    int n = nbase + nt * 16 + r16;
                    float bias = cb3[n0 + n];
                    #pragma unroll
                    for (int reg = 0; reg < 4; ++reg) {
                        int r = mh * 32 + mt * 16 + g * 4 + reg;
                        out_cov[(size_t)(sbase + r) * 1024 + n0 + n] = acc[mt][nt][reg] + bias;
                    }
                }
        }
    }

    if (contr) {
        #pragma unroll
        for (int mt = 0; mt < 2; ++mt)
            #pragma unroll
            for (int reg = 0; reg < 4; ++reg) {
                float v = pp[mt][reg];
                v += __shfl_xor(v, 1, 64);
                v += __shfl_xor(v, 2, 64);
                v += __shfl_xor(v, 4, 64);
                v += __shfl_xor(v, 8, 64);
                pp[mt][reg] = v;
            }
        if (r16 == 0) {
            #pragma unroll
            for (int mt = 0; mt < 2; ++mt)
                #pragma unroll
                for (int reg = 0; reg < 4; ++reg) {
                    int r = mh * 32 + mt * 16 + g * 4 + reg;
                    red[nq][r] = pp[mt][reg];
                }
        }
        __syncthreads();
        if (tid < 64) {
            float v = red[0][tid] + red[1][tid];
            int sg = sbase + tid;
            if (job == 0) out_trace[sg] = v;
            else          out_cdiv[(size_t)sg * Dd + (job - 1)] = v;
        }
    }
}

// ============================================================================
extern "C" void kernel_launch(void* const* d_in, const int* in_sizes, int n_in,
                              void* d_out, int out_size, void* d_ws, size_t ws_size,
                              hipStream_t stream) {
    const float* x   = (const float*)d_in[0];
    const float* sW1 = (const float*)d_in[1];
    const float* sb1 = (const float*)d_in[2];
    const float* sW2 = (const float*)d_in[3];
    const float* sb2 = (const float*)d_in[4];
    const float* sW3 = (const float*)d_in[5];
    const float* sb3 = (const float*)d_in[6];
    const float* cW1 = (const float*)d_in[7];
    const float* cb1 = (const float*)d_in[8];
    const float* cW2 = (const float*)d_in[9];
    const float* cb2 = (const float*)d_in[10];
    const float* cW3 = (const float*)d_in[11];
    const float* cb3 = (const float*)d_in[12];

    const int B = in_sizes[0] / Dd;   // 2048

    float* out       = (float*)d_out;
    float* out_score = out;                                  // [B,32]
    float* out_trace = out + (size_t)B * Dd;                 // [B]
    float* out_cov   = out_trace + B;                        // [B,32,32]
    float* out_cdiv  = out_cov + (size_t)B * Dd * Dd;        // [B,32]

    unsigned short* ws16 = (unsigned short*)d_ws;
    const size_t SZ = (size_t)B * 256;
    unsigned short* T1s  = ws16;
    unsigned short* T2s  = ws16 + SZ;
    unsigned short* T1c  = ws16 + 2 * SZ;
    unsigned short* T2c  = ws16 + 3 * SZ;
    unsigned short* H2c  = ws16 + 4 * SZ;
    unsigned short* Mt   = ws16 + 5 * SZ;                    // [33][256][256]
    unsigned short* cW3t = Mt + (size_t)33 * 65536;          // [1024][256]

    const int nfwd = B / 2;
    ka_fused<<<dim3(nfwd + 132 + 32), dim3(256), 0, stream>>>(
        x, sW1, sb1, sW2, sb2, sW3, sb3,
        cW1, cb1, cW2, cb2, cW3,
        out_score, T1s, T2s, T1c, T2c, H2c, Mt, cW3t, B);

    kb_mfma<<<dim3(B / 64, 37), dim3(256), 0, stream>>>(
        T1s, T2s, T1c, T2c, H2c, Mt, cW3t, cb3,
        out_trace, out_cdiv, out_cov);
}